// Round 1
// baseline (5436.308 us; speedup 1.0000x reference)
//
#include <hip/hip_runtime.h>
#include <hip/hip_bf16.h>
#include <math.h>

// Model constants (from reference)
#define SEQ   2048
#define NP    128
#define DM    64
#define NL    8
#define NCLS  11

// LDS layout (float words). Total 38912 words = 155648 B (< 160 KiB/CU).
#define OFF_H   0        // h[128][64]
#define OFF_QO  8192     // q, later o[128][64]; later W2 staging [128][64]
#define OFF_KT  16384    // k^T [64][128]; later r=o@Wo [128][64]; later W1 lo
#define OFF_V   24576    // v[128][64]; later W1 hi (W1 spans KT..V = 16384 w)
#define OFF_W   32768    // staged 64x64 weight
#define OFF_AR  36864    // per-wave attn rows 4*512; later f_lds[16][128]
#define LDS_WORDS 38912

__device__ __forceinline__ float geluf(float v) {
    return 0.5f * v * (1.0f + erff(v * 0.70710678118654752f));
}
__device__ __forceinline__ float glu_pair(float a, float b) {
    return a * geluf(b) + b * geluf(a);
}
__device__ __forceinline__ float wave_sum(float v) {
#pragma unroll
    for (int off = 32; off; off >>= 1) v += __shfl_xor(v, off);
    return v;
}
__device__ __forceinline__ float wave_max(float v) {
#pragma unroll
    for (int off = 32; off; off >>= 1) v = fmaxf(v, __shfl_xor(v, off));
    return v;
}

// acc = sum_c lds[hoff + c] * lds[woff + c*64 + lane]   (64-long dot)
__device__ __forceinline__ float dot64(const float* lds, int hoff, int woff, int lane) {
    const float4* h4 = (const float4*)&lds[hoff];
    float acc = 0.f;
#pragma unroll
    for (int c4 = 0; c4 < 16; ++c4) {
        float4 hv = h4[c4];
        int c = c4 * 4;
        acc += hv.x * lds[woff + (c + 0) * 64 + lane];
        acc += hv.y * lds[woff + (c + 1) * 64 + lane];
        acc += hv.z * lds[woff + (c + 2) * 64 + lane];
        acc += hv.w * lds[woff + (c + 3) * 64 + lane];
    }
    return acc;
}

extern "C" __global__ __launch_bounds__(256, 1)
void feat_fwd(const float* __restrict__ x, const float* __restrict__ frame_W,
              const float* __restrict__ cls_token, const float* __restrict__ pos_embed,
              const float* __restrict__ Wq, const float* __restrict__ Wk,
              const float* __restrict__ Wv, const float* __restrict__ Wmix,
              const float* __restrict__ Wo, const float* __restrict__ ln1_g,
              const float* __restrict__ ln1_b, const float* __restrict__ ln2_g,
              const float* __restrict__ ln2_b, const float* __restrict__ W1,
              const float* __restrict__ b1, const float* __restrict__ W2,
              const float* __restrict__ b2, const float* __restrict__ Wc,
              const float* __restrict__ bc, float* __restrict__ out,
              __hip_bfloat16* __restrict__ aw) {
    extern __shared__ float lds[];
    const int t = threadIdx.x, lane = t & 63, wv = t >> 6;
    const int b = blockIdx.x;

    auto stage = [&](const float* src, int off, int nwords) {
        const float4* s4 = (const float4*)src;
        float4* d4 = (float4*)&lds[off];
        for (int i = t; i < (nwords >> 2); i += 256) d4[i] = s4[i];
    };

    // ---------------- patch embed ----------------
    stage(frame_W, OFF_W, 4096);
    __syncthreads();
    for (int n = wv; n < 127; n += 4) {
        float acc = 0.f;
        const float* xb = x + ((size_t)b * SEQ + n * 16) * 2;
#pragma unroll
        for (int c = 0; c < 32; ++c) {
            float2 xv = *(const float2*)&xb[c * 2];   // (ch0, ch1) = patch[c], patch[c+32]
            acc += xv.x * lds[OFF_W + c * 64 + lane];
            acc += xv.y * lds[OFF_W + (c + 32) * 64 + lane];
        }
        lds[OFF_H + n * 64 + lane] = acc + pos_embed[n * 64 + lane];
    }
    if (t < 64) lds[OFF_H + 127 * 64 + t] = cls_token[t] + pos_embed[127 * 64 + t];
    __syncthreads();

    // ---------------- layers ----------------
    for (int l = 0; l < NL; ++l) {
        float wm[4][4];
#pragma unroll
        for (int hh = 0; hh < 4; ++hh)
#pragma unroll
            for (int g = 0; g < 4; ++g) wm[hh][g] = Wmix[l * 16 + hh * 4 + g];
        const float g1v = ln1_g[l * 64 + lane], be1v = ln1_b[l * 64 + lane];
        const float g2v = ln2_g[l * 64 + lane], be2v = ln2_b[l * 64 + lane];
        const float b2v = b2[l * 64 + lane];

        // ---- q = (h @ Wq) / 4 ----
        stage(Wq + l * 4096, OFF_W, 4096);
        __syncthreads();
        for (int r = 0; r < 32; ++r) {
            int n = wv * 32 + r;
            float acc = dot64(lds, OFF_H + n * 64, OFF_W, lane);
            lds[OFF_QO + n * 64 + lane] = acc * 0.25f;
        }
        __syncthreads();
        // ---- k^T ----
        stage(Wk + l * 4096, OFF_W, 4096);
        __syncthreads();
        for (int r = 0; r < 32; ++r) {
            int n = wv * 32 + r;
            float acc = dot64(lds, OFF_H + n * 64, OFF_W, lane);
            lds[OFF_KT + lane * 128 + n] = acc;   // k^T[c=lane][j=n]
        }
        __syncthreads();
        // ---- v ----
        stage(Wv + l * 4096, OFF_W, 4096);
        __syncthreads();
        for (int r = 0; r < 32; ++r) {
            int n = wv * 32 + r;
            float acc = dot64(lds, OFF_H + n * 64, OFF_W, lane);
            lds[OFF_V + n * 64 + lane] = acc;
        }
        __syncthreads();

        // ---- attention: per row i, per-head logits -> head mix -> +residual -> softmax -> PV ----
        for (int i8 = 0; i8 < 32; ++i8) {
            const int i = wv + 4 * i8;
            float lh[4][2] = {{0, 0}, {0, 0}, {0, 0}, {0, 0}};
            const float4* q4 = (const float4*)&lds[OFF_QO + i * 64];
#pragma unroll
            for (int c4 = 0; c4 < 16; ++c4) {
                float4 qv = q4[c4];
                int c = c4 * 4;
                int hh = c4 >> 2;                 // head = c/16, constant per unrolled iter
                lh[hh][0] += qv.x * lds[OFF_KT + (c + 0) * 128 + lane];
                lh[hh][1] += qv.x * lds[OFF_KT + (c + 0) * 128 + lane + 64];
                lh[hh][0] += qv.y * lds[OFF_KT + (c + 1) * 128 + lane];
                lh[hh][1] += qv.y * lds[OFF_KT + (c + 1) * 128 + lane + 64];
                lh[hh][0] += qv.z * lds[OFF_KT + (c + 2) * 128 + lane];
                lh[hh][1] += qv.z * lds[OFF_KT + (c + 2) * 128 + lane + 64];
                lh[hh][0] += qv.w * lds[OFF_KT + (c + 3) * 128 + lane];
                lh[hh][1] += qv.w * lds[OFF_KT + (c + 3) * 128 + lane + 64];
            }
#pragma unroll
            for (int g = 0; g < 4; ++g) {
                float l0 = lh[0][0] * wm[0][g] + lh[1][0] * wm[1][g] + lh[2][0] * wm[2][g] + lh[3][0] * wm[3][g];
                float l1 = lh[0][1] * wm[0][g] + lh[1][1] * wm[1][g] + lh[2][1] * wm[2][g] + lh[3][1] * wm[3][g];
                const int wsb = ((b * 4 + g) * 128 + i) * 128;
                if (l > 0) {
                    l0 += __bfloat162float(aw[wsb + lane]);
                    l1 += __bfloat162float(aw[wsb + lane + 64]);
                }
                float m = wave_max(fmaxf(l0, l1));
                float p0 = __expf(l0 - m), p1 = __expf(l1 - m);
                float s = wave_sum(p0 + p1);
                float inv = 1.f / s;
                float a0 = p0 * inv, a1 = p1 * inv;
                if (l < NL - 1) {
                    aw[wsb + lane] = __float2bfloat16(a0);
                    aw[wsb + lane + 64] = __float2bfloat16(a1);
                }
                lds[OFF_AR + wv * 512 + g * 128 + lane] = a0;
                lds[OFF_AR + wv * 512 + g * 128 + lane + 64] = a1;
            }
            __syncthreads();
            // PV: lane = output column c = g*16+dd
            const int g2 = lane >> 4;
            const float4* arow = (const float4*)&lds[OFF_AR + wv * 512 + g2 * 128];
            float acc = 0.f;
#pragma unroll
            for (int j4 = 0; j4 < 32; ++j4) {
                float4 av = arow[j4];
                int j = j4 * 4;
                acc += av.x * lds[OFF_V + (j + 0) * 64 + lane];
                acc += av.y * lds[OFF_V + (j + 1) * 64 + lane];
                acc += av.z * lds[OFF_V + (j + 2) * 64 + lane];
                acc += av.w * lds[OFF_V + (j + 3) * 64 + lane];
            }
            lds[OFF_QO + i * 64 + lane] = acc;   // o row (q row i already consumed by this wave)
        }
        __syncthreads();

        // ---- r = o @ Wo; h = LN1(h + r) ----
        stage(Wo + l * 4096, OFF_W, 4096);
        __syncthreads();
        for (int r = 0; r < 32; ++r) {
            int n = wv * 32 + r;
            float acc = dot64(lds, OFF_QO + n * 64, OFF_W, lane);
            lds[OFF_KT + n * 64 + lane] = acc;
        }
        __syncthreads();
        for (int i8 = 0; i8 < 32; ++i8) {
            int i = wv + 4 * i8;
            float val = lds[OFF_H + i * 64 + lane] + lds[OFF_KT + i * 64 + lane];
            float mean = wave_sum(val) * 0.015625f;
            float dv = val - mean;
            float var = wave_sum(dv * dv) * 0.015625f;
            lds[OFF_H + i * 64 + lane] = dv * rsqrtf(var + 1e-5f) * g1v + be1v;
        }
        __syncthreads();

        // ---- FFN: u = h@W1+b1 ; f = u1*gelu(u2)+u2*gelu(u1) ; h = LN2(h + f@W2+b2) ----
        stage(W1 + l * 16384, OFF_KT, 16384);   // spans KT+V regions
        stage(W2 + l * 8192, OFF_QO, 8192);
        __syncthreads();
        const int nn = t >> 4;          // row-in-block 0..15
        const int mb = (t & 15) * 8;    // m base 0..120
        const float4 b1a = *(const float4*)&b1[l * 256 + mb];
        const float4 b1b = *(const float4*)&b1[l * 256 + mb + 4];
        const float4 b1c = *(const float4*)&b1[l * 256 + 128 + mb];
        const float4 b1d = *(const float4*)&b1[l * 256 + 132 + mb];
        for (int blk = 0; blk < 8; ++blk) {
            const int n = blk * 16 + nn;
            float4 u1a = b1a, u1b = b1b, u2a = b1c, u2b = b1d;
            for (int c = 0; c < 64; ++c) {
                float hc = lds[OFF_H + n * 64 + c];
                const float4* w1p = (const float4*)&lds[OFF_KT + c * 256 + mb];
                const float4* w2p = (const float4*)&lds[OFF_KT + c * 256 + 128 + mb];
                float4 wa = w1p[0], wb = w1p[1];
                float4 wc2 = w2p[0], wd = w2p[1];
                u1a.x += hc * wa.x;  u1a.y += hc * wa.y;  u1a.z += hc * wa.z;  u1a.w += hc * wa.w;
                u1b.x += hc * wb.x;  u1b.y += hc * wb.y;  u1b.z += hc * wb.z;  u1b.w += hc * wb.w;
                u2a.x += hc * wc2.x; u2a.y += hc * wc2.y; u2a.z += hc * wc2.z; u2a.w += hc * wc2.w;
                u2b.x += hc * wd.x;  u2b.y += hc * wd.y;  u2b.z += hc * wd.z;  u2b.w += hc * wd.w;
            }
            float4 f0, f1;
            f0.x = glu_pair(u1a.x, u2a.x); f0.y = glu_pair(u1a.y, u2a.y);
            f0.z = glu_pair(u1a.z, u2a.z); f0.w = glu_pair(u1a.w, u2a.w);
            f1.x = glu_pair(u1b.x, u2b.x); f1.y = glu_pair(u1b.y, u2b.y);
            f1.z = glu_pair(u1b.z, u2b.z); f1.w = glu_pair(u1b.w, u2b.w);
            *(float4*)&lds[OFF_AR + nn * 128 + mb] = f0;
            *(float4*)&lds[OFF_AR + nn * 128 + mb + 4] = f1;
            __syncthreads();
#pragma unroll
            for (int k = 0; k < 4; ++k) {
                const int r2 = wv * 4 + k;
                const float4* frow = (const float4*)&lds[OFF_AR + r2 * 128];
                float acc = b2v;
#pragma unroll
                for (int m4 = 0; m4 < 32; ++m4) {
                    float4 fv = frow[m4];
                    int m = m4 * 4;
                    acc += fv.x * lds[OFF_QO + (m + 0) * 64 + lane];
                    acc += fv.y * lds[OFF_QO + (m + 1) * 64 + lane];
                    acc += fv.z * lds[OFF_QO + (m + 2) * 64 + lane];
                    acc += fv.w * lds[OFF_QO + (m + 3) * 64 + lane];
                }
                const int row = blk * 16 + r2;
                float val = lds[OFF_H + row * 64 + lane] + acc;
                float mean = wave_sum(val) * 0.015625f;
                float dv = val - mean;
                float var = wave_sum(dv * dv) * 0.015625f;
                lds[OFF_H + row * 64 + lane] = dv * rsqrtf(var + 1e-5f) * g2v + be2v;
            }
            __syncthreads();
        }
    }

    // ---------------- classifier head (row 127) ----------------
    if (t == 0) {
        float lg[NCLS];
        float mx = -1e30f;
#pragma unroll
        for (int c = 0; c < NCLS; ++c) {
            float a = bc[c];
            for (int d = 0; d < 64; ++d) a += lds[OFF_H + 127 * 64 + d] * Wc[d * NCLS + c];
            lg[c] = a;
            mx = fmaxf(mx, a);
        }
        float s = 0.f;
#pragma unroll
        for (int c = 0; c < NCLS; ++c) { lg[c] = __expf(lg[c] - mx); s += lg[c]; }
        float inv = 1.f / s;
#pragma unroll
        for (int c = 0; c < NCLS; ++c) out[b * NCLS + c] = lg[c] * inv;
    }
}

extern "C" void kernel_launch(void* const* d_in, const int* in_sizes, int n_in,
                              void* d_out, int out_size, void* d_ws, size_t ws_size,
                              hipStream_t stream) {
    const float* x         = (const float*)d_in[0];
    const float* frame_W   = (const float*)d_in[1];
    const float* cls_token = (const float*)d_in[2];
    const float* pos_embed = (const float*)d_in[3];
    const float* Wq        = (const float*)d_in[4];
    const float* Wk        = (const float*)d_in[5];
    const float* Wv        = (const float*)d_in[6];
    const float* Wmix      = (const float*)d_in[7];
    const float* Wo        = (const float*)d_in[8];
    const float* ln1_g     = (const float*)d_in[9];
    const float* ln1_b     = (const float*)d_in[10];
    const float* ln2_g     = (const float*)d_in[11];
    const float* ln2_b     = (const float*)d_in[12];
    const float* W1        = (const float*)d_in[13];
    const float* b1        = (const float*)d_in[14];
    const float* W2        = (const float*)d_in[15];
    const float* b2        = (const float*)d_in[16];
    const float* Wc        = (const float*)d_in[17];
    const float* bc        = (const float*)d_in[18];
    float* out = (float*)d_out;
    __hip_bfloat16* aw = (__hip_bfloat16*)d_ws;   // attn residual carry: 256*4*128*128 bf16 = 33.5 MB

    const int lds_bytes = LDS_WORDS * 4;
    hipFuncSetAttribute((const void*)feat_fwd, hipFuncAttributeMaxDynamicSharedMemorySize, lds_bytes);
    feat_fwd<<<dim3(256), dim3(256), lds_bytes, stream>>>(
        x, frame_W, cls_token, pos_embed, Wq, Wk, Wv, Wmix, Wo,
        ln1_g, ln1_b, ln2_g, ln2_b, W1, b1, W2, b2, Wc, bc, out, aw);
}

// Round 3
// 624.506 us; speedup vs baseline: 8.7050x; 8.7050x over previous
//
#include <hip/hip_runtime.h>
#include <hip/hip_bf16.h>
#include <math.h>

typedef short s16x8 __attribute__((ext_vector_type(8)));
typedef short s16x4 __attribute__((ext_vector_type(4)));
typedef _Float16 f16x8 __attribute__((ext_vector_type(8)));
typedef float f32x4 __attribute__((ext_vector_type(4)));

#define MFMA(a, b, c) \
  __builtin_amdgcn_mfma_f32_16x16x32_f16(__builtin_bit_cast(f16x8, a), \
                                         __builtin_bit_cast(f16x8, b), c, 0, 0, 0)

// d_ws layout: [0, 33.5MB) attn-prob carry fp16 [b][g][i][j]; then weight frags.
#define CARRY_BYTES 33554432UL
#define OFF_FWB 0
#define OFF_WQB 8192
#define OFF_WKB 73728
#define OFF_WVB 139264
#define OFF_WOB 204800
#define OFF_W1B 270336
#define OFF_W2B 532480
// total weight frag bytes = 663552; ws needed = 34,217,984 B

// LDS (bytes)
#define L_HFP 0       // fp32 h[128][64]                    32768
#define L_HA  32768   // f16 A-frags of h    [8 mt][2 ks]   16384
#define L_QOA 49152   // qA (P1->P2) / oA (P3->P4)          16384
#define L_KB  65536   // kB [8 jt][2 ks]                    16384
#define L_VB  81920   // vB [4 nt][4 ks]                    16384
#define L_FA  65536   // fA [8 mt][4 ks] (overlaps KB/VB)   32768
#define LDS_BYTES 98304

// Fragment slot: element (idx, k) of an A[M x K] (idx=m) or B[K x N] (idx=n)
// matrix, frag-linear tiles of 1024B. Same bijection used by every writer and
// reader of a given GEMM => contraction correct regardless of HW k-order.
__device__ __forceinline__ int fragSlotByte(int idx, int k, int KS) {
  return ((((idx >> 4) * KS + (k >> 5)) << 10)
        | (((idx & 15) | (((k >> 2) & 3) << 4)) << 4)
        | (((k & 3) | (((k >> 4) & 1) << 2)) << 1));
}
__device__ __forceinline__ short f2h(float f) {
  _Float16 h = (_Float16)f;
  return __builtin_bit_cast(short, h);
}
__device__ __forceinline__ float h2f(short s) {
  return (float)__builtin_bit_cast(_Float16, s);
}
__device__ __forceinline__ float geluf(float v) {
  return 0.5f * v * (1.0f + erff(v * 0.70710678118654752f));
}
__device__ __forceinline__ s16x8 fragL(const char* lds, int off, int tile, int lane) {
  return *(const s16x8*)(lds + off + (tile << 10) + (lane << 4));
}
__device__ __forceinline__ s16x8 fragG(const char* wb, int tile, int lane) {
  return *(const s16x8*)(wb + (tile << 10) + (lane << 4));
}

// ---------------- weight prep: fp32 [L][K][N] -> f16 B-frag-linear ----------------
extern "C" __global__ void prep_w(const float* __restrict__ src, char* __restrict__ dst,
                                  int K, int N, int L, float scale) {
  const int KS = K >> 5;
  const int tot = L * K * N;
  for (int e = blockIdx.x * blockDim.x + threadIdx.x; e < tot; e += gridDim.x * blockDim.x) {
    const int l = e / (K * N), rem = e - l * (K * N);
    const int k = rem / N, n = rem - k * N;
    *(short*)(dst + (size_t)l * K * N * 2 + fragSlotByte(n, k, KS)) = f2h(src[e] * scale);
  }
}

// ---------------- main fused kernel: 1 block = 1 batch, 8 waves ----------------
extern "C" __global__ __launch_bounds__(512)
void feat_fwd(const float* __restrict__ x, const float* __restrict__ cls_token,
              const float* __restrict__ pos_embed, const float* __restrict__ Wmix,
              const float* __restrict__ ln1_g, const float* __restrict__ ln1_b,
              const float* __restrict__ ln2_g, const float* __restrict__ ln2_b,
              const float* __restrict__ b1, const float* __restrict__ b2,
              const float* __restrict__ Wc, const float* __restrict__ bc,
              float* __restrict__ out, unsigned short* aw, const char* __restrict__ wfrag) {
  extern __shared__ char lds[];
  const int tid = threadIdx.x, lane = tid & 63, wv = tid >> 6, b = blockIdx.x;
  float* hf = (float*)(lds + L_HFP);
  const f32x4 Z4 = {0.f, 0.f, 0.f, 0.f};

  // ---- P0: patch embed via MFMA (A from x, B = frame_W frags) ----
  {
    const int it = wv;
    s16x8 a[2];
#pragma unroll
    for (int ks = 0; ks < 2; ++ks) {
      s16x8 av;
#pragma unroll
      for (int j = 0; j < 8; ++j) {
        const int fp = (lane >> 4) * 4 + (j & 3) + 16 * (j >> 2) + 32 * ks;
        const int fr = fp & 31, ch = fp >> 5;
        const int tok = it * 16 + (lane & 15);
        int sidx = tok * 16 + fr; if (sidx > 2047) sidx = 2047;  // row 127 overridden below
        av[j] = f2h(x[((size_t)b * 2048 + sidx) * 2 + ch]);
      }
      a[ks] = av;
    }
    const char* fwb = wfrag + OFF_FWB;
    f32x4 acc[4];
#pragma unroll
    for (int nt = 0; nt < 4; ++nt) {
      acc[nt] = Z4;
      acc[nt] = MFMA(a[0], fragG(fwb, nt * 2 + 0, lane), acc[nt]);
      acc[nt] = MFMA(a[1], fragG(fwb, nt * 2 + 1, lane), acc[nt]);
    }
#pragma unroll
    for (int nt = 0; nt < 4; ++nt)
#pragma unroll
      for (int r = 0; r < 4; ++r) {
        const int i = it * 16 + (lane >> 4) * 4 + r;
        const int c = nt * 16 + (lane & 15);
        float v = acc[nt][r] + pos_embed[i * 64 + c];
        if (i == 127) v = cls_token[c] + pos_embed[127 * 64 + c];
        hf[i * 64 + c] = v;
        *(short*)(lds + L_HA + fragSlotByte(i, c, 2)) = f2h(v);
      }
  }
  __syncthreads();

  for (int l = 0; l < 8; ++l) {
    // ---- P1: q,k,v = h @ W (wave = row-tile it) ----
    {
      const int it = wv;
      const s16x8 ha0 = fragL(lds, L_HA, it * 2 + 0, lane);
      const s16x8 ha1 = fragL(lds, L_HA, it * 2 + 1, lane);
      const int rb = it * 16 + (lane >> 4) * 4, cb = lane & 15;
      {
        const char* wq = wfrag + OFF_WQB + l * 8192;  // pre-scaled by 1/4
        f32x4 acc[4];
#pragma unroll
        for (int nt = 0; nt < 4; ++nt) {
          acc[nt] = Z4;
          acc[nt] = MFMA(ha0, fragG(wq, nt * 2 + 0, lane), acc[nt]);
          acc[nt] = MFMA(ha1, fragG(wq, nt * 2 + 1, lane), acc[nt]);
        }
#pragma unroll
        for (int nt = 0; nt < 4; ++nt)
#pragma unroll
          for (int r = 0; r < 4; ++r)  // qA: A-frag(m=i, k=c)
            *(short*)(lds + L_QOA + fragSlotByte(rb + r, nt * 16 + cb, 2)) = f2h(acc[nt][r]);
      }
      {
        const char* wk = wfrag + OFF_WKB + l * 8192;
        f32x4 acc[4];
#pragma unroll
        for (int nt = 0; nt < 4; ++nt) {
          acc[nt] = Z4;
          acc[nt] = MFMA(ha0, fragG(wk, nt * 2 + 0, lane), acc[nt]);
          acc[nt] = MFMA(ha1, fragG(wk, nt * 2 + 1, lane), acc[nt]);
        }
#pragma unroll
        for (int nt = 0; nt < 4; ++nt)
#pragma unroll
          for (int r = 0; r < 4; ++r)  // kB: B-frag(n=j, k=c)
            *(short*)(lds + L_KB + fragSlotByte(rb + r, nt * 16 + cb, 2)) = f2h(acc[nt][r]);
      }
      {
        const char* wvp = wfrag + OFF_WVB + l * 8192;
        f32x4 acc[4];
#pragma unroll
        for (int nt = 0; nt < 4; ++nt) {
          acc[nt] = Z4;
          acc[nt] = MFMA(ha0, fragG(wvp, nt * 2 + 0, lane), acc[nt]);
          acc[nt] = MFMA(ha1, fragG(wvp, nt * 2 + 1, lane), acc[nt]);
        }
#pragma unroll
        for (int nt = 0; nt < 4; ++nt)
#pragma unroll
          for (int r = 0; r < 4; ++r)  // vB: B-frag(n=col, k=row j), K=128
            *(short*)(lds + L_VB + fragSlotByte(nt * 16 + cb, rb + r, 4)) = f2h(acc[nt][r]);
      }
    }
    __syncthreads();

    // ---- P2: logits_g = (q .* wmix_g) @ k^T  + carry -> softmax -> carry ----
    {
      const int g = wv >> 1, ih = wv & 1;
      float wm[4];
#pragma unroll
      for (int h = 0; h < 4; ++h) wm[h] = Wmix[(l * 4 + h) * 4 + g];
      f32x4 acc[4][8];
#pragma unroll
      for (int a = 0; a < 4; ++a)
#pragma unroll
        for (int j = 0; j < 8; ++j) acc[a][j] = Z4;
#pragma unroll
      for (int ks = 0; ks < 2; ++ks) {
        s16x8 qs[4];
#pragma unroll
        for (int q4 = 0; q4 < 4; ++q4) {
          s16x8 qf = fragL(lds, L_QOA, (ih * 4 + q4) * 2 + ks, lane);
#pragma unroll
          for (int e = 0; e < 8; ++e)  // head of elem e is 2*ks + (e>>2)
            qf[e] = f2h(h2f(qf[e]) * wm[2 * ks + (e >> 2)]);
          qs[q4] = qf;
        }
#pragma unroll
        for (int jt = 0; jt < 8; ++jt) {
          const s16x8 kf = fragL(lds, L_KB, jt * 2 + ks, lane);
#pragma unroll
          for (int q4 = 0; q4 < 4; ++q4) acc[q4][jt] = MFMA(qs[q4], kf, acc[q4][jt]);
        }
      }
      unsigned short* awp = aw + (((size_t)b * 4 + g) << 14);
#pragma unroll
      for (int q4 = 0; q4 < 4; ++q4)
#pragma unroll
        for (int r = 0; r < 4; ++r) {
          const int i = (ih * 4 + q4) * 16 + (lane >> 4) * 4 + r;
          float v[8];
#pragma unroll
          for (int jt = 0; jt < 8; ++jt) v[jt] = acc[q4][jt][r];
          if (l > 0) {
#pragma unroll
            for (int jt = 0; jt < 8; ++jt)
              v[jt] += h2f((short)awp[i * 128 + jt * 16 + (lane & 15)]);
          }
          float m = v[0];
#pragma unroll
          for (int jt = 1; jt < 8; ++jt) m = fmaxf(m, v[jt]);
          m = fmaxf(m, __shfl_xor(m, 1)); m = fmaxf(m, __shfl_xor(m, 2));
          m = fmaxf(m, __shfl_xor(m, 4)); m = fmaxf(m, __shfl_xor(m, 8));
          float e8[8], s = 0.f;
#pragma unroll
          for (int jt = 0; jt < 8; ++jt) { e8[jt] = __expf(v[jt] - m); s += e8[jt]; }
          s += __shfl_xor(s, 1); s += __shfl_xor(s, 2);
          s += __shfl_xor(s, 4); s += __shfl_xor(s, 8);
          const float inv = 1.f / s;
#pragma unroll
          for (int jt = 0; jt < 8; ++jt)
            awp[i * 128 + jt * 16 + (lane & 15)] = (unsigned short)f2h(e8[jt] * inv);
        }
    }
    __syncthreads();  // qA fully consumed before oA overwrites L_QOA

    // ---- P3: o_g = p_g @ v_g (A-frags straight from own carry rows, L1-warm) ----
    {
      const int g = wv >> 1, ih = wv & 1;
      const unsigned short* awp = aw + (((size_t)b * 4 + g) << 14);
      f32x4 acc[4];
#pragma unroll
      for (int q4 = 0; q4 < 4; ++q4) acc[q4] = Z4;
#pragma unroll
      for (int ks = 0; ks < 4; ++ks) {
        const s16x8 bf = fragL(lds, L_VB, g * 4 + ks, lane);
#pragma unroll
        for (int q4 = 0; q4 < 4; ++q4) {
          const int i = (ih * 4 + q4) * 16 + (lane & 15);
          const unsigned short* pp = awp + i * 128 + ks * 32 + (lane >> 4) * 4;
          const s16x4 lo = *(const s16x4*)pp;
          const s16x4 hi = *(const s16x4*)(pp + 16);
          s16x8 af;
          af[0] = lo[0]; af[1] = lo[1]; af[2] = lo[2]; af[3] = lo[3];
          af[4] = hi[0]; af[5] = hi[1]; af[6] = hi[2]; af[7] = hi[3];
          acc[q4] = MFMA(af, bf, acc[q4]);
        }
      }
#pragma unroll
      for (int q4 = 0; q4 < 4; ++q4)
#pragma unroll
        for (int r = 0; r < 4; ++r)  // oA: A-frag(m=i, k = g*16+d)
          *(short*)(lds + L_QOA +
                    fragSlotByte((ih * 4 + q4) * 16 + (lane >> 4) * 4 + r, g * 16 + (lane & 15), 2))
              = f2h(acc[q4][r]);
    }
    __syncthreads();

    // ---- P4: r = o @ Wo ; h = LN1(h + r) -> hf + hA ----
    {
      const int it = wv;
      const s16x8 a0 = fragL(lds, L_QOA, it * 2 + 0, lane);
      const s16x8 a1 = fragL(lds, L_QOA, it * 2 + 1, lane);
      const char* wo = wfrag + OFF_WOB + l * 8192;
      f32x4 acc[4];
#pragma unroll
      for (int nt = 0; nt < 4; ++nt) {
        acc[nt] = Z4;
        acc[nt] = MFMA(a0, fragG(wo, nt * 2 + 0, lane), acc[nt]);
        acc[nt] = MFMA(a1, fragG(wo, nt * 2 + 1, lane), acc[nt]);
      }
      float g1v[4], b1v[4];
#pragma unroll
      for (int nt = 0; nt < 4; ++nt) {
        const int c = nt * 16 + (lane & 15);
        g1v[nt] = ln1_g[l * 64 + c]; b1v[nt] = ln1_b[l * 64 + c];
      }
#pragma unroll
      for (int r = 0; r < 4; ++r) {
        const int i = it * 16 + (lane >> 4) * 4 + r;
        float v[4];
#pragma unroll
        for (int nt = 0; nt < 4; ++nt) v[nt] = hf[i * 64 + nt * 16 + (lane & 15)] + acc[nt][r];
        float s = v[0] + v[1] + v[2] + v[3];
        s += __shfl_xor(s, 1); s += __shfl_xor(s, 2); s += __shfl_xor(s, 4); s += __shfl_xor(s, 8);
        const float mu = s * 0.015625f;
        float d[4], sq = 0.f;
#pragma unroll
        for (int nt = 0; nt < 4; ++nt) { d[nt] = v[nt] - mu; sq += d[nt] * d[nt]; }
        sq += __shfl_xor(sq, 1); sq += __shfl_xor(sq, 2);
        sq += __shfl_xor(sq, 4); sq += __shfl_xor(sq, 8);
        const float rs = rsqrtf(sq * 0.015625f + 1e-5f);
#pragma unroll
        for (int nt = 0; nt < 4; ++nt) {
          const int c = nt * 16 + (lane & 15);
          const float o = d[nt] * rs * g1v[nt] + b1v[nt];
          hf[i * 64 + c] = o;
          *(short*)(lds + L_HA + fragSlotByte(i, c, 2)) = f2h(o);
        }
      }
    }
    __syncthreads();

    // ---- P5: u = h@W1 + b1 ; f = u1*gelu(u2)+u2*gelu(u1) -> fA ----
    // wave owns output cols nt = wv and wv+8 so GLU pairs stay in-wave
    {
      const char* w1 = wfrag + OFF_W1B + l * 32768;
      const int mcol = wv * 16 + (lane & 15);
      const float bia = b1[l * 256 + mcol], bib = b1[l * 256 + 128 + mcol];
      f32x4 acc[8][2];
#pragma unroll
      for (int it = 0; it < 8; ++it) { acc[it][0] = Z4; acc[it][1] = Z4; }
#pragma unroll
      for (int ks = 0; ks < 2; ++ks) {
        const s16x8 bf0 = fragG(w1, wv * 2 + ks, lane);
        const s16x8 bf1 = fragG(w1, (wv + 8) * 2 + ks, lane);
#pragma unroll
        for (int it = 0; it < 8; ++it) {
          const s16x8 af = fragL(lds, L_HA, it * 2 + ks, lane);
          acc[it][0] = MFMA(af, bf0, acc[it][0]);
          acc[it][1] = MFMA(af, bf1, acc[it][1]);
        }
      }
#pragma unroll
      for (int it = 0; it < 8; ++it)
#pragma unroll
        for (int r = 0; r < 4; ++r) {
          const float u1 = acc[it][0][r] + bia, u2 = acc[it][1][r] + bib;
          const float f = u1 * geluf(u2) + u2 * geluf(u1);
          *(short*)(lds + L_FA + fragSlotByte(it * 16 + (lane >> 4) * 4 + r, mcol, 4)) = f2h(f);
        }
    }
    __syncthreads();

    // ---- P6: h = LN2(h + f@W2 + b2) -> hf + hA ----
    {
      const int it = wv;
      const char* w2 = wfrag + OFF_W2B + l * 16384;
      f32x4 acc[4];
#pragma unroll
      for (int nt = 0; nt < 4; ++nt) acc[nt] = Z4;
#pragma unroll
      for (int ks = 0; ks < 4; ++ks) {
        const s16x8 af = fragL(lds, L_FA, it * 4 + ks, lane);
#pragma unroll
        for (int nt = 0; nt < 4; ++nt) acc[nt] = MFMA(af, fragG(w2, nt * 4 + ks, lane), acc[nt]);
      }
      float g2v[4], b2v[4], bb[4];
#pragma unroll
      for (int nt = 0; nt < 4; ++nt) {
        const int c = nt * 16 + (lane & 15);
        g2v[nt] = ln2_g[l * 64 + c]; b2v[nt] = ln2_b[l * 64 + c]; bb[nt] = b2[l * 64 + c];
      }
#pragma unroll
      for (int r = 0; r < 4; ++r) {
        const int i = it * 16 + (lane >> 4) * 4 + r;
        float v[4];
#pragma unroll
        for (int nt = 0; nt < 4; ++nt)
          v[nt] = hf[i * 64 + nt * 16 + (lane & 15)] + acc[nt][r] + bb[nt];
        float s = v[0] + v[1] + v[2] + v[3];
        s += __shfl_xor(s, 1); s += __shfl_xor(s, 2); s += __shfl_xor(s, 4); s += __shfl_xor(s, 8);
        const float mu = s * 0.015625f;
        float d[4], sq = 0.f;
#pragma unroll
        for (int nt = 0; nt < 4; ++nt) { d[nt] = v[nt] - mu; sq += d[nt] * d[nt]; }
        sq += __shfl_xor(sq, 1); sq += __shfl_xor(sq, 2);
        sq += __shfl_xor(sq, 4); sq += __shfl_xor(sq, 8);
        const float rs = rsqrtf(sq * 0.015625f + 1e-5f);
#pragma unroll
        for (int nt = 0; nt < 4; ++nt) {
          const int c = nt * 16 + (lane & 15);
          const float o = d[nt] * rs * g2v[nt] + b2v[nt];
          hf[i * 64 + c] = o;
          *(short*)(lds + L_HA + fragSlotByte(i, c, 2)) = f2h(o);
        }
      }
    }
    __syncthreads();
  }

  // ---- classifier head: softmax(h[127] @ Wc + bc) ----
  if (wv == 0) {
    const float hc = hf[127 * 64 + lane];
    float lg[11];
#pragma unroll
    for (int kc = 0; kc < 11; ++kc) {
      float p = hc * Wc[lane * 11 + kc];
      p += __shfl_xor(p, 1);  p += __shfl_xor(p, 2);  p += __shfl_xor(p, 4);
      p += __shfl_xor(p, 8);  p += __shfl_xor(p, 16); p += __shfl_xor(p, 32);
      lg[kc] = p + bc[kc];
    }
    float mx = lg[0];
#pragma unroll
    for (int kc = 1; kc < 11; ++kc) mx = fmaxf(mx, lg[kc]);
    float s = 0.f;
#pragma unroll
    for (int kc = 0; kc < 11; ++kc) s += __expf(lg[kc] - mx);
    const float inv = 1.f / s;
    if (lane < 11) out[b * 11 + lane] = __expf(lg[lane] - mx) * inv;
  }
}

extern "C" void kernel_launch(void* const* d_in, const int* in_sizes, int n_in,
                              void* d_out, int out_size, void* d_ws, size_t ws_size,
                              hipStream_t stream) {
  const float* x         = (const float*)d_in[0];
  const float* frame_W   = (const float*)d_in[1];
  const float* cls_token = (const float*)d_in[2];
  const float* pos_embed = (const float*)d_in[3];
  const float* Wq        = (const float*)d_in[4];
  const float* Wk        = (const float*)d_in[5];
  const float* Wv        = (const float*)d_in[6];
  const float* Wmix      = (const float*)d_in[7];
  const float* Wo        = (const float*)d_in[8];
  const float* ln1_g     = (const float*)d_in[9];
  const float* ln1_b     = (const float*)d_in[10];
  const float* ln2_g     = (const float*)d_in[11];
  const float* ln2_b     = (const float*)d_in[12];
  const float* W1        = (const float*)d_in[13];
  const float* b1        = (const float*)d_in[14];
  const float* W2        = (const float*)d_in[15];
  const float* b2        = (const float*)d_in[16];
  const float* Wc        = (const float*)d_in[17];
  const float* bc        = (const float*)d_in[18];
  float* out = (float*)d_out;
  unsigned short* aw = (unsigned short*)d_ws;            // carry, 33.5 MB (fp16)
  char* wfrag = (char*)d_ws + CARRY_BYTES;               // weight frags, 648 KB

  // convert weights to f16 B-frag layout (every call; deterministic)
  prep_w<<<64, 256, 0, stream>>>(frame_W, wfrag + OFF_FWB, 64, 64, 1, 1.0f);
  prep_w<<<64, 256, 0, stream>>>(Wq, wfrag + OFF_WQB, 64, 64, 8, 0.25f);  // fold 1/sqrt(DQK)
  prep_w<<<64, 256, 0, stream>>>(Wk, wfrag + OFF_WKB, 64, 64, 8, 1.0f);
  prep_w<<<64, 256, 0, stream>>>(Wv, wfrag + OFF_WVB, 64, 64, 8, 1.0f);
  prep_w<<<64, 256, 0, stream>>>(Wo, wfrag + OFF_WOB, 64, 64, 8, 1.0f);
  prep_w<<<128, 256, 0, stream>>>(W1, wfrag + OFF_W1B, 64, 256, 8, 1.0f);
  prep_w<<<128, 256, 0, stream>>>(W2, wfrag + OFF_W2B, 128, 64, 8, 1.0f);

  hipFuncSetAttribute((const void*)feat_fwd, hipFuncAttributeMaxDynamicSharedMemorySize, LDS_BYTES);
  feat_fwd<<<dim3(256), dim3(512), LDS_BYTES, stream>>>(
      x, cls_token, pos_embed, Wmix, ln1_g, ln1_b, ln2_g, ln2_b,
      b1, b2, Wc, bc, out, aw, wfrag);
}

// Round 4
// 193.545 us; speedup vs baseline: 28.0880x; 3.2267x over previous
//
#include <hip/hip_runtime.h>
#include <hip/hip_bf16.h>
#include <math.h>

typedef short s16x8 __attribute__((ext_vector_type(8)));
typedef _Float16 f16x8 __attribute__((ext_vector_type(8)));
typedef float f32x4 __attribute__((ext_vector_type(4)));

#define MFMA(a, b, c) \
  __builtin_amdgcn_mfma_f32_16x16x32_f16(__builtin_bit_cast(f16x8, a), \
                                         __builtin_bit_cast(f16x8, b), c, 0, 0, 0)

// d_ws: weight frags only (carry now lives in registers)
#define OFF_FWB 0
#define OFF_WQB 8192
#define OFF_WKB 73728
#define OFF_WVB 139264
#define OFF_WOB 204800
#define OFF_W1B 270336
#define OFF_W2B 532480
// total 663552 B

// LDS (bytes)
#define L_HFP 0       // fp32 h[128][64]                    32768
#define L_HA  32768   // f16 A-frags of h    [8 mt][2 ks]   16384
#define L_QOA 49152   // qA (P1->P2) / oA (P3->P4)          16384
#define L_KB  65536   // kB [8 jt][2 ks]                    16384
#define L_VB  81920   // vB [4 nt][4 ks]                    16384
#define L_FA  65536   // fA [8 mt][4 ks] (overlaps KB/VB)   32768
#define LDS_BYTES 98304

// Fragment slot: element (idx, k) of an A[MxK] (idx=m) or B[KxN] (idx=n) matrix,
// frag-linear 1024B tiles. lane = (idx&15) | (((k>>2)&3)<<4);
// elem = (k&3) | (((k>>4)&1)<<2); tile = (idx>>4)*KS + (k>>5).
__device__ __forceinline__ int fragSlotByte(int idx, int k, int KS) {
  return ((((idx >> 4) * KS + (k >> 5)) << 10)
        | (((idx & 15) | (((k >> 2) & 3) << 4)) << 4)
        | (((k & 3) | (((k >> 4) & 1) << 2)) << 1));
}
__device__ __forceinline__ short f2h(float f) {
  _Float16 h = (_Float16)f;
  return __builtin_bit_cast(short, h);
}
__device__ __forceinline__ float h2f(short s) {
  return (float)__builtin_bit_cast(_Float16, s);
}
__device__ __forceinline__ float geluf(float v) {
  return 0.5f * v * (1.0f + erff(v * 0.70710678118654752f));
}
__device__ __forceinline__ s16x8 fragL(const char* lds, int off, int tile, int lane) {
  return *(const s16x8*)(lds + off + (tile << 10) + (lane << 4));
}
__device__ __forceinline__ s16x8 fragG(const char* wb, int tile, int lane) {
  return *(const s16x8*)(wb + (tile << 10) + (lane << 4));
}

// ---------------- single prep kernel: all weights fp32 -> f16 frag-linear ----------------
extern "C" __global__ void prep_all(const float* __restrict__ fw, const float* __restrict__ wq,
                                    const float* __restrict__ wk, const float* __restrict__ wv,
                                    const float* __restrict__ wo, const float* __restrict__ w1,
                                    const float* __restrict__ w2, char* __restrict__ dst) {
  for (int e = blockIdx.x * blockDim.x + threadIdx.x; e < 331776; e += gridDim.x * blockDim.x) {
    const float* src; int dstoff, K, N, rel; float sc = 1.f;
    if (e < 4096)        { src = fw; dstoff = OFF_FWB; K = 64;  N = 64;  rel = e; }
    else if (e < 36864)  { src = wq; dstoff = OFF_WQB; K = 64;  N = 64;  rel = e - 4096; sc = 0.25f; }
    else if (e < 69632)  { src = wk; dstoff = OFF_WKB; K = 64;  N = 64;  rel = e - 36864; }
    else if (e < 102400) { src = wv; dstoff = OFF_WVB; K = 64;  N = 64;  rel = e - 69632; }
    else if (e < 135168) { src = wo; dstoff = OFF_WOB; K = 64;  N = 64;  rel = e - 102400; }
    else if (e < 266240) { src = w1; dstoff = OFF_W1B; K = 64;  N = 256; rel = e - 135168; }
    else                 { src = w2; dstoff = OFF_W2B; K = 128; N = 64;  rel = e - 266240; }
    const int KS = K >> 5, pl = K * N;
    const int l = rel / pl, r2 = rel - l * pl;
    const int k = r2 / N, n = r2 - k * N;
    *(short*)(dst + dstoff + (size_t)l * pl * 2 + fragSlotByte(n, k, KS)) = f2h(src[rel] * sc);
  }
}

// ---------------- main fused kernel: 1 block = 1 batch, 8 waves ----------------
extern "C" __global__ __launch_bounds__(512)
void feat_fwd(const float* __restrict__ x, const float* __restrict__ cls_token,
              const float* __restrict__ pos_embed, const float* __restrict__ Wmix,
              const float* __restrict__ ln1_g, const float* __restrict__ ln1_b,
              const float* __restrict__ ln2_g, const float* __restrict__ ln2_b,
              const float* __restrict__ b1, const float* __restrict__ b2,
              const float* __restrict__ Wc, const float* __restrict__ bc,
              float* __restrict__ out, const char* __restrict__ wfrag) {
  extern __shared__ char lds[];
  const int tid = threadIdx.x, lane = tid & 63, wv = tid >> 6, b = blockIdx.x;
  float* hf = (float*)(lds + L_HFP);
  const f32x4 Z4 = {0.f, 0.f, 0.f, 0.f};

  // attention-prob carry, register-resident across layers.
  // af[q4][ks] elem e holds p[i][j]: i=(ih*4+q4)*16+(lane&15),
  // j = jt*16+(lane>>4)*4+r with jt=(ks<<1)|(e>>2), r=e&3. (== A-frag(m=i,k=j))
  s16x8 af[4][4] = {};

  // ---- P0: patch embed via MFMA ----
  {
    const int it = wv;
    s16x8 a[2];
#pragma unroll
    for (int ks = 0; ks < 2; ++ks) {
      s16x8 av;
#pragma unroll
      for (int j = 0; j < 8; ++j) {
        const int fp = (lane >> 4) * 4 + (j & 3) + 16 * (j >> 2) + 32 * ks;
        const int fr = fp & 31, ch = fp >> 5;
        const int tok = it * 16 + (lane & 15);
        int sidx = tok * 16 + fr; if (sidx > 2047) sidx = 2047;  // row 127 overridden below
        av[j] = f2h(x[((size_t)b * 2048 + sidx) * 2 + ch]);
      }
      a[ks] = av;
    }
    const char* fwb = wfrag + OFF_FWB;
    f32x4 acc[4];
#pragma unroll
    for (int nt = 0; nt < 4; ++nt) {
      acc[nt] = Z4;
      acc[nt] = MFMA(a[0], fragG(fwb, nt * 2 + 0, lane), acc[nt]);
      acc[nt] = MFMA(a[1], fragG(fwb, nt * 2 + 1, lane), acc[nt]);
    }
#pragma unroll
    for (int nt = 0; nt < 4; ++nt)
#pragma unroll
      for (int r = 0; r < 4; ++r) {
        const int i = it * 16 + (lane >> 4) * 4 + r;
        const int c = nt * 16 + (lane & 15);
        float v = acc[nt][r] + pos_embed[i * 64 + c];
        if (i == 127) v = cls_token[c] + pos_embed[127 * 64 + c];
        hf[i * 64 + c] = v;
        *(short*)(lds + L_HA + fragSlotByte(i, c, 2)) = f2h(v);
      }
  }
  __syncthreads();

  for (int l = 0; l < 8; ++l) {
    // ---- P1: q,k,v = h @ W (wave = row-tile it) ----
    {
      const int it = wv;
      const s16x8 ha0 = fragL(lds, L_HA, it * 2 + 0, lane);
      const s16x8 ha1 = fragL(lds, L_HA, it * 2 + 1, lane);
      const int rb = it * 16 + (lane >> 4) * 4, cb = lane & 15;
      {
        const char* wq = wfrag + OFF_WQB + l * 8192;  // pre-scaled by 1/4
        f32x4 acc[4];
#pragma unroll
        for (int nt = 0; nt < 4; ++nt) {
          acc[nt] = Z4;
          acc[nt] = MFMA(ha0, fragG(wq, nt * 2 + 0, lane), acc[nt]);
          acc[nt] = MFMA(ha1, fragG(wq, nt * 2 + 1, lane), acc[nt]);
        }
#pragma unroll
        for (int nt = 0; nt < 4; ++nt)
#pragma unroll
          for (int r = 0; r < 4; ++r)  // qA: frag(idx=i, k=c)
            *(short*)(lds + L_QOA + fragSlotByte(rb + r, nt * 16 + cb, 2)) = f2h(acc[nt][r]);
      }
      {
        const char* wk = wfrag + OFF_WKB + l * 8192;
        f32x4 acc[4];
#pragma unroll
        for (int nt = 0; nt < 4; ++nt) {
          acc[nt] = Z4;
          acc[nt] = MFMA(ha0, fragG(wk, nt * 2 + 0, lane), acc[nt]);
          acc[nt] = MFMA(ha1, fragG(wk, nt * 2 + 1, lane), acc[nt]);
        }
#pragma unroll
        for (int nt = 0; nt < 4; ++nt)
#pragma unroll
          for (int r = 0; r < 4; ++r)  // kF: frag(idx=j, k=c)
            *(short*)(lds + L_KB + fragSlotByte(rb + r, nt * 16 + cb, 2)) = f2h(acc[nt][r]);
      }
      {
        const char* wvp = wfrag + OFF_WVB + l * 8192;
        f32x4 acc[4];
#pragma unroll
        for (int nt = 0; nt < 4; ++nt) {
          acc[nt] = Z4;
          acc[nt] = MFMA(ha0, fragG(wvp, nt * 2 + 0, lane), acc[nt]);
          acc[nt] = MFMA(ha1, fragG(wvp, nt * 2 + 1, lane), acc[nt]);
        }
#pragma unroll
        for (int nt = 0; nt < 4; ++nt)
#pragma unroll
          for (int r = 0; r < 4; ++r)  // vB: frag(idx=col, k=row j), KS=4
            *(short*)(lds + L_VB + fragSlotByte(nt * 16 + cb, rb + r, 4)) = f2h(acc[nt][r]);
      }
    }
    __syncthreads();

    // ---- P2: S^T = K @ (q*wmix)^T  (+ reg carry) -> softmax -> af regs ----
    {
      const int g = wv >> 1, ih = wv & 1;
      float wm[4];
#pragma unroll
      for (int h = 0; h < 4; ++h) wm[h] = Wmix[(l * 4 + h) * 4 + g];
#pragma unroll
      for (int q4 = 0; q4 < 4; ++q4) {
        f32x4 acc[8];
#pragma unroll
        for (int jt = 0; jt < 8; ++jt) acc[jt] = Z4;
#pragma unroll
        for (int ks = 0; ks < 2; ++ks) {
          s16x8 qf = fragL(lds, L_QOA, (ih * 4 + q4) * 2 + ks, lane);
#pragma unroll
          for (int e = 0; e < 8; ++e)  // head of elem e: c>>4 = 2*ks + (e>>2)
            qf[e] = f2h(h2f(qf[e]) * wm[2 * ks + (e >> 2)]);
#pragma unroll
          for (int jt = 0; jt < 8; ++jt) {
            const s16x8 kf = fragL(lds, L_KB, jt * 2 + ks, lane);
            acc[jt] = MFMA(kf, qf, acc[jt]);  // A=k (m=j), B=q (n=i)
          }
        }
        // softmax over j: 32 in-lane (jt,r) x 4 lane-groups
        float v[8][4];
#pragma unroll
        for (int jt = 0; jt < 8; ++jt)
#pragma unroll
          for (int r = 0; r < 4; ++r) {
            float t = acc[jt][r];
            if (l > 0) t += h2f(af[q4][jt >> 1][r | ((jt & 1) << 2)]);
            v[jt][r] = t;
          }
        float m = v[0][0];
#pragma unroll
        for (int jt = 0; jt < 8; ++jt)
#pragma unroll
          for (int r = 0; r < 4; ++r) m = fmaxf(m, v[jt][r]);
        m = fmaxf(m, __shfl_xor(m, 16)); m = fmaxf(m, __shfl_xor(m, 32));
        float s = 0.f;
#pragma unroll
        for (int jt = 0; jt < 8; ++jt)
#pragma unroll
          for (int r = 0; r < 4; ++r) { v[jt][r] = __expf(v[jt][r] - m); s += v[jt][r]; }
        s += __shfl_xor(s, 16); s += __shfl_xor(s, 32);
        const float inv = 1.f / s;
#pragma unroll
        for (int jt = 0; jt < 8; ++jt)
#pragma unroll
          for (int r = 0; r < 4; ++r)
            af[q4][jt >> 1][r | ((jt & 1) << 2)] = f2h(v[jt][r] * inv);
      }
    }
    __syncthreads();  // qA fully consumed before oA overwrites L_QOA

    // ---- P3: o_g = p_g @ v_g (A = af regs) ----
    {
      const int g = wv >> 1, ih = wv & 1;
#pragma unroll
      for (int q4 = 0; q4 < 4; ++q4) {
        f32x4 acc = Z4;
#pragma unroll
        for (int ks = 0; ks < 4; ++ks)
          acc = MFMA(af[q4][ks], fragL(lds, L_VB, g * 4 + ks, lane), acc);
#pragma unroll
        for (int r = 0; r < 4; ++r)  // oA: frag(idx=i, k=g*16+d)
          *(short*)(lds + L_QOA +
                    fragSlotByte((ih * 4 + q4) * 16 + (lane >> 4) * 4 + r, g * 16 + (lane & 15), 2))
              = f2h(acc[r]);
      }
    }
    __syncthreads();

    // ---- P4: r = o @ Wo ; h = LN1(h + r) -> hf + hA ----
    {
      const int it = wv;
      const s16x8 a0 = fragL(lds, L_QOA, it * 2 + 0, lane);
      const s16x8 a1 = fragL(lds, L_QOA, it * 2 + 1, lane);
      const char* wo = wfrag + OFF_WOB + l * 8192;
      f32x4 acc[4];
#pragma unroll
      for (int nt = 0; nt < 4; ++nt) {
        acc[nt] = Z4;
        acc[nt] = MFMA(a0, fragG(wo, nt * 2 + 0, lane), acc[nt]);
        acc[nt] = MFMA(a1, fragG(wo, nt * 2 + 1, lane), acc[nt]);
      }
      float g1v[4], b1v[4];
#pragma unroll
      for (int nt = 0; nt < 4; ++nt) {
        const int c = nt * 16 + (lane & 15);
        g1v[nt] = ln1_g[l * 64 + c]; b1v[nt] = ln1_b[l * 64 + c];
      }
#pragma unroll
      for (int r = 0; r < 4; ++r) {
        const int i = it * 16 + (lane >> 4) * 4 + r;
        float v[4];
#pragma unroll
        for (int nt = 0; nt < 4; ++nt) v[nt] = hf[i * 64 + nt * 16 + (lane & 15)] + acc[nt][r];
        float s = v[0] + v[1] + v[2] + v[3];
        s += __shfl_xor(s, 1); s += __shfl_xor(s, 2); s += __shfl_xor(s, 4); s += __shfl_xor(s, 8);
        const float mu = s * 0.015625f;
        float d[4], sq = 0.f;
#pragma unroll
        for (int nt = 0; nt < 4; ++nt) { d[nt] = v[nt] - mu; sq += d[nt] * d[nt]; }
        sq += __shfl_xor(sq, 1); sq += __shfl_xor(sq, 2);
        sq += __shfl_xor(sq, 4); sq += __shfl_xor(sq, 8);
        const float rs = rsqrtf(sq * 0.015625f + 1e-5f);
#pragma unroll
        for (int nt = 0; nt < 4; ++nt) {
          const int c = nt * 16 + (lane & 15);
          const float o = d[nt] * rs * g1v[nt] + b1v[nt];
          hf[i * 64 + c] = o;
          *(short*)(lds + L_HA + fragSlotByte(i, c, 2)) = f2h(o);
        }
      }
    }
    __syncthreads();

    // ---- P5: u = h@W1 + b1 ; f = u1*gelu(u2)+u2*gelu(u1) -> fA ----
    {
      const char* w1 = wfrag + OFF_W1B + l * 32768;
      const int mcol = wv * 16 + (lane & 15);
      const float bia = b1[l * 256 + mcol], bib = b1[l * 256 + 128 + mcol];
      f32x4 acc[8][2];
#pragma unroll
      for (int it = 0; it < 8; ++it) { acc[it][0] = Z4; acc[it][1] = Z4; }
#pragma unroll
      for (int ks = 0; ks < 2; ++ks) {
        const s16x8 bf0 = fragG(w1, wv * 2 + ks, lane);
        const s16x8 bf1 = fragG(w1, (wv + 8) * 2 + ks, lane);
#pragma unroll
        for (int it = 0; it < 8; ++it) {
          const s16x8 af2 = fragL(lds, L_HA, it * 2 + ks, lane);
          acc[it][0] = MFMA(af2, bf0, acc[it][0]);
          acc[it][1] = MFMA(af2, bf1, acc[it][1]);
        }
      }
#pragma unroll
      for (int it = 0; it < 8; ++it)
#pragma unroll
        for (int r = 0; r < 4; ++r) {
          const float u1 = acc[it][0][r] + bia, u2 = acc[it][1][r] + bib;
          const float f = u1 * geluf(u2) + u2 * geluf(u1);
          *(short*)(lds + L_FA + fragSlotByte(it * 16 + (lane >> 4) * 4 + r, mcol, 4)) = f2h(f);
        }
    }
    __syncthreads();

    // ---- P6: h = LN2(h + f@W2 + b2) -> hf + hA ----
    {
      const int it = wv;
      const char* w2 = wfrag + OFF_W2B + l * 16384;
      f32x4 acc[4];
#pragma unroll
      for (int nt = 0; nt < 4; ++nt) acc[nt] = Z4;
#pragma unroll
      for (int ks = 0; ks < 4; ++ks) {
        const s16x8 af2 = fragL(lds, L_FA, it * 4 + ks, lane);
#pragma unroll
        for (int nt = 0; nt < 4; ++nt) acc[nt] = MFMA(af2, fragG(w2, nt * 4 + ks, lane), acc[nt]);
      }
      float g2v[4], b2v[4], bb[4];
#pragma unroll
      for (int nt = 0; nt < 4; ++nt) {
        const int c = nt * 16 + (lane & 15);
        g2v[nt] = ln2_g[l * 64 + c]; b2v[nt] = ln2_b[l * 64 + c]; bb[nt] = b2[l * 64 + c];
      }
#pragma unroll
      for (int r = 0; r < 4; ++r) {
        const int i = it * 16 + (lane >> 4) * 4 + r;
        float v[4];
#pragma unroll
        for (int nt = 0; nt < 4; ++nt)
          v[nt] = hf[i * 64 + nt * 16 + (lane & 15)] + acc[nt][r] + bb[nt];
        float s = v[0] + v[1] + v[2] + v[3];
        s += __shfl_xor(s, 1); s += __shfl_xor(s, 2); s += __shfl_xor(s, 4); s += __shfl_xor(s, 8);
        const float mu = s * 0.015625f;
        float d[4], sq = 0.f;
#pragma unroll
        for (int nt = 0; nt < 4; ++nt) { d[nt] = v[nt] - mu; sq += d[nt] * d[nt]; }
        sq += __shfl_xor(sq, 1); sq += __shfl_xor(sq, 2);
        sq += __shfl_xor(sq, 4); sq += __shfl_xor(sq, 8);
        const float rs = rsqrtf(sq * 0.015625f + 1e-5f);
#pragma unroll
        for (int nt = 0; nt < 4; ++nt) {
          const int c = nt * 16 + (lane & 15);
          const float o = d[nt] * rs * g2v[nt] + b2v[nt];
          hf[i * 64 + c] = o;
          *(short*)(lds + L_HA + fragSlotByte(i, c, 2)) = f2h(o);
        }
      }
    }
    __syncthreads();
  }

  // ---- classifier head: softmax(h[127] @ Wc + bc) ----
  if (wv == 0) {
    const float hc = hf[127 * 64 + lane];
    float lg[11];
#pragma unroll
    for (int kc = 0; kc < 11; ++kc) {
      float p = hc * Wc[lane * 11 + kc];
      p += __shfl_xor(p, 1);  p += __shfl_xor(p, 2);  p += __shfl_xor(p, 4);
      p += __shfl_xor(p, 8);  p += __shfl_xor(p, 16); p += __shfl_xor(p, 32);
      lg[kc] = p + bc[kc];
    }
    float mx = lg[0];
#pragma unroll
    for (int kc = 1; kc < 11; ++kc) mx = fmaxf(mx, lg[kc]);
    float s = 0.f;
#pragma unroll
    for (int kc = 0; kc < 11; ++kc) s += __expf(lg[kc] - mx);
    const float inv = 1.f / s;
    if (lane < 11) out[b * 11 + lane] = __expf(lg[lane] - mx) * inv;
  }
}

extern "C" void kernel_launch(void* const* d_in, const int* in_sizes, int n_in,
                              void* d_out, int out_size, void* d_ws, size_t ws_size,
                              hipStream_t stream) {
  const float* x         = (const float*)d_in[0];
  const float* frame_W   = (const float*)d_in[1];
  const float* cls_token = (const float*)d_in[2];
  const float* pos_embed = (const float*)d_in[3];
  const float* Wq        = (const float*)d_in[4];
  const float* Wk        = (const float*)d_in[5];
  const float* Wv        = (const float*)d_in[6];
  const float* Wmix      = (const float*)d_in[7];
  const float* Wo        = (const float*)d_in[8];
  const float* ln1_g     = (const float*)d_in[9];
  const float* ln1_b     = (const float*)d_in[10];
  const float* ln2_g     = (const float*)d_in[11];
  const float* ln2_b     = (const float*)d_in[12];
  const float* W1        = (const float*)d_in[13];
  const float* b1        = (const float*)d_in[14];
  const float* W2        = (const float*)d_in[15];
  const float* b2        = (const float*)d_in[16];
  const float* Wc        = (const float*)d_in[17];
  const float* bc        = (const float*)d_in[18];
  float* out = (float*)d_out;
  char* wfrag = (char*)d_ws;  // 663,552 B of f16 weight fragments

  prep_all<<<162, 256, 0, stream>>>(frame_W, Wq, Wk, Wv, Wo, W1, W2, wfrag);

  hipFuncSetAttribute((const void*)feat_fwd, hipFuncAttributeMaxDynamicSharedMemorySize, LDS_BYTES);
  feat_fwd<<<dim3(256), dim3(512), LDS_BYTES, stream>>>(
      x, cls_token, pos_embed, Wmix, ln1_g, ln1_b, ln2_g, ln2_b,
      b1, b2, Wc, bc, out, wfrag);
}

// Round 6
// 154.247 us; speedup vs baseline: 35.2442x; 1.2548x over previous
//
#include <hip/hip_runtime.h>
#include <hip/hip_bf16.h>
#include <math.h>

typedef short s16x8 __attribute__((ext_vector_type(8)));
typedef short s16x4 __attribute__((ext_vector_type(4)));
typedef _Float16 f16x8 __attribute__((ext_vector_type(8)));
typedef float f32x4 __attribute__((ext_vector_type(4)));

#define MFMA(a, b, c) \
  __builtin_amdgcn_mfma_f32_16x16x32_f16(__builtin_bit_cast(f16x8, a), \
                                         __builtin_bit_cast(f16x8, b), c, 0, 0, 0)

// d_ws: f16 weight fragments only
#define OFF_FWB 0
#define OFF_WQB 8192
#define OFF_WKB 73728
#define OFF_WVB 139264
#define OFF_WOB 204800
#define OFF_W1B 270336
#define OFF_W2B 532480
// total 663552 B

// LDS (bytes): four 16KB frag buffers
#define L_Q 0
#define L_K 16384
#define L_V 32768
#define L_O 49152
#define LDS_BYTES 65536

// Fragment slot bijection (prep kernel only): element (idx,k) of frag-linear 1KB tiles.
__device__ __forceinline__ int fragSlotByte(int idx, int k, int KS) {
  return ((((idx >> 4) * KS + (k >> 5)) << 10)
        | (((idx & 15) | (((k >> 2) & 3) << 4)) << 4)
        | (((k & 3) | (((k >> 4) & 1) << 2)) << 1));
}
__device__ __forceinline__ short f2h(float f) {
  _Float16 h = (_Float16)f;
  return __builtin_bit_cast(short, h);
}
__device__ __forceinline__ float h2f(short s) {
  return (float)__builtin_bit_cast(_Float16, s);
}
__device__ __forceinline__ unsigned pk_u32(float a, float b) {
  return __builtin_bit_cast(unsigned, __builtin_amdgcn_cvt_pkrtz(a, b));
}
// erf via Abramowitz-Stegun 7.1.26 (|err|<=1.5e-7), exp/rcp on trans pipe
__device__ __forceinline__ float geluf(float v) {
  float z = fabsf(v) * 0.70710678118654752f;
  float t = 1.0f / (1.0f + 0.3275911f * z);
  float p = t * (0.254829592f + t * (-0.284496736f + t * (1.421413741f +
            t * (-1.453152027f + t * 1.061405429f))));
  float erfv = 1.0f - p * __expf(-z * z);
  erfv = copysignf(erfv, v);
  return 0.5f * v * (1.0f + erfv);
}
__device__ __forceinline__ s16x8 pack8(const f32x4& a, const f32x4& b) {
  union { unsigned u[4]; s16x8 s; } z;
  z.u[0] = pk_u32(a[0], a[1]);
  z.u[1] = pk_u32(a[2], a[3]);
  z.u[2] = pk_u32(b[0], b[1]);
  z.u[3] = pk_u32(b[2], b[3]);
  return z.s;
}
__device__ __forceinline__ s16x4 pack4(const f32x4& a) {
  union { unsigned u[2]; s16x4 s; } z;
  z.u[0] = pk_u32(a[0], a[1]);
  z.u[1] = pk_u32(a[2], a[3]);
  return z.s;
}
__device__ __forceinline__ s16x8 fragL(const char* lds, int off, int tile, int lane) {
  return *(const s16x8*)(lds + off + (tile << 10) + (lane << 4));
}
__device__ __forceinline__ s16x8 fragG(const char* wb, int tile, int lane) {
  return *(const s16x8*)(wb + (tile << 10) + (lane << 4));
}

// ---------------- weight prep: all fp32 weights -> f16 frag-linear ----------------
extern "C" __global__ void prep_all(const float* __restrict__ fw, const float* __restrict__ wq,
                                    const float* __restrict__ wk, const float* __restrict__ wv,
                                    const float* __restrict__ wo, const float* __restrict__ w1,
                                    const float* __restrict__ w2, char* __restrict__ dst) {
  for (int e = blockIdx.x * blockDim.x + threadIdx.x; e < 331776; e += gridDim.x * blockDim.x) {
    const float* src; int dstoff, K, N, rel; float sc = 1.f;
    if (e < 4096)        { src = fw; dstoff = OFF_FWB; K = 64;  N = 64;  rel = e; }
    else if (e < 36864)  { src = wq; dstoff = OFF_WQB; K = 64;  N = 64;  rel = e - 4096; sc = 0.25f; }
    else if (e < 69632)  { src = wk; dstoff = OFF_WKB; K = 64;  N = 64;  rel = e - 36864; }
    else if (e < 102400) { src = wv; dstoff = OFF_WVB; K = 64;  N = 64;  rel = e - 69632; }
    else if (e < 135168) { src = wo; dstoff = OFF_WOB; K = 64;  N = 64;  rel = e - 102400; }
    else if (e < 266240) { src = w1; dstoff = OFF_W1B; K = 64;  N = 256; rel = e - 135168; }
    else                 { src = w2; dstoff = OFF_W2B; K = 128; N = 64;  rel = e - 266240; }
    const int KS = K >> 5, pl = K * N;
    const int l = rel / pl, r2 = rel - l * pl;
    const int k = r2 / N, n = r2 - k * N;
    *(short*)(dst + dstoff + (size_t)l * pl * 2 + fragSlotByte(n, k, KS)) = f2h(src[rel] * sc);
  }
}

// ---------------- main fused kernel: 1 block = 1 batch, 8 waves ----------------
extern "C" __global__ __launch_bounds__(512)
void feat_fwd(const float* __restrict__ x, const float* __restrict__ cls_token,
              const float* __restrict__ pos_embed, const float* __restrict__ Wmix,
              const float* __restrict__ ln1_g, const float* __restrict__ ln1_b,
              const float* __restrict__ ln2_g, const float* __restrict__ ln2_b,
              const float* __restrict__ b1, const float* __restrict__ b2,
              const float* __restrict__ Wc, const float* __restrict__ bc,
              float* __restrict__ out, const char* __restrict__ wfrag) {
  extern __shared__ char lds[];
  const int tid = threadIdx.x, lane = tid & 63, wv = tid >> 6, b = blockIdx.x;
  const int l15 = lane & 15, g16 = lane >> 4;
  const f32x4 Z4 = {0.f, 0.f, 0.f, 0.f};

  // Register state (per lane):
  //  hr[nt][r] = h[i][c] fp32, i = wv*16 + l15, c = nt*16 + g16*4 + r
  //  hp[ks]    = h as f16 frag (A or B role), k-range [ks*32, ks*32+32)
  //  af[q4][ks]= attn-prob carry, frag(idx=i', k=j), i' = (ih*4+q4)*16 + l15
  f32x4 hr[4];
  s16x8 hp[2];
  s16x8 af[4][4] = {};

  // ---- P0: patch embed (W as A, x as B) -> hr regs ----
  {
    const int i0 = wv * 16 + l15;
    s16x8 xB[2];
#pragma unroll
    for (int ks = 0; ks < 2; ++ks) {
      f32x4 lo, hi;
#pragma unroll
      for (int e = 0; e < 8; ++e) {
        int sidx = i0 * 16 + (e >> 2) * 16 + g16 * 4 + (e & 3);
        if (sidx > 2047) sidx = 2047;  // i0==127 lanes overridden below
        float xv = x[((size_t)b * 2048 + sidx) * 2 + ks];
        if (e < 4) lo[e] = xv; else hi[e - 4] = xv;
      }
      xB[ks] = pack8(lo, hi);
    }
    const char* fwb = wfrag + OFF_FWB;
#pragma unroll
    for (int nt = 0; nt < 4; ++nt) {
      f32x4 a = Z4;
      a = MFMA(fragG(fwb, nt * 2 + 0, lane), xB[0], a);
      a = MFMA(fragG(fwb, nt * 2 + 1, lane), xB[1], a);
      const float4 p4 = *(const float4*)&pos_embed[i0 * 64 + nt * 16 + g16 * 4];
#pragma unroll
      for (int r = 0; r < 4; ++r) hr[nt][r] = a[r] + (&p4.x)[r];
    }
    if (i0 == 127) {
#pragma unroll
      for (int nt = 0; nt < 4; ++nt) {
        const float4 c4 = *(const float4*)&cls_token[nt * 16 + g16 * 4];
        const float4 p4 = *(const float4*)&pos_embed[127 * 64 + nt * 16 + g16 * 4];
#pragma unroll
        for (int r = 0; r < 4; ++r) hr[nt][r] = (&c4.x)[r] + (&p4.x)[r];
      }
    }
    hp[0] = pack8(hr[0], hr[1]);
    hp[1] = pack8(hr[2], hr[3]);
  }

  for (int l = 0; l < 8; ++l) {
    // ---- P1: q,k (swapped: W as A) and v (normal) from hp regs -> LDS frags ----
    {
      const char* wq = wfrag + OFF_WQB + l * 8192;
      const char* wk = wfrag + OFF_WKB + l * 8192;
      const char* wvp = wfrag + OFF_WVB + l * 8192;
      f32x4 aq[4], ak[4], av[4];
#pragma unroll
      for (int nt = 0; nt < 4; ++nt) { aq[nt] = Z4; ak[nt] = Z4; av[nt] = Z4; }
#pragma unroll
      for (int ks = 0; ks < 2; ++ks)
#pragma unroll
        for (int nt = 0; nt < 4; ++nt) {
          aq[nt] = MFMA(fragG(wq, nt * 2 + ks, lane), hp[ks], aq[nt]);
          ak[nt] = MFMA(fragG(wk, nt * 2 + ks, lane), hp[ks], ak[nt]);
          av[nt] = MFMA(hp[ks], fragG(wvp, nt * 2 + ks, lane), av[nt]);
        }
#pragma unroll
      for (int ksp = 0; ksp < 2; ++ksp) {
        *(s16x8*)(lds + L_Q + (((wv * 2 + ksp) << 10) | (lane << 4))) = pack8(aq[2 * ksp], aq[2 * ksp + 1]);
        *(s16x8*)(lds + L_K + (((wv * 2 + ksp) << 10) | (lane << 4))) = pack8(ak[2 * ksp], ak[2 * ksp + 1]);
      }
#pragma unroll
      for (int nt = 0; nt < 4; ++nt)  // v transposed frag: idx=vcol, k=row
        *(s16x4*)(lds + L_V + (((nt * 4 + (wv >> 1)) << 10) | (lane << 4) | ((wv & 1) << 3))) = pack4(av[nt]);
    }
    __syncthreads();

    // ---- P2: S^T per head g (A=k, B=q*wmix) + reg carry -> softmax -> af ----
    {
      const int g = wv >> 1, ih = wv & 1;
      s16x8 wmv[2];
      {
        const float w0 = Wmix[(l * 4 + 0) * 4 + g], w1_ = Wmix[(l * 4 + 1) * 4 + g];
        const float w2_ = Wmix[(l * 4 + 2) * 4 + g], w3_ = Wmix[(l * 4 + 3) * 4 + g];
        union { unsigned u[4]; s16x8 s; } u0, u1;
        u0.u[0] = u0.u[1] = pk_u32(w0, w0);
        u0.u[2] = u0.u[3] = pk_u32(w1_, w1_);
        u1.u[0] = u1.u[1] = pk_u32(w2_, w2_);
        u1.u[2] = u1.u[3] = pk_u32(w3_, w3_);
        wmv[0] = u0.s; wmv[1] = u1.s;
      }
#pragma unroll
      for (int q4 = 0; q4 < 4; ++q4) {
        const int ti = ih * 4 + q4;
        f32x4 acc[8];
#pragma unroll
        for (int jt = 0; jt < 8; ++jt) acc[jt] = Z4;
#pragma unroll
        for (int ks = 0; ks < 2; ++ks) {
          const s16x8 qr = fragL(lds, L_Q, ti * 2 + ks, lane);
          const f16x8 qm = __builtin_bit_cast(f16x8, qr) * __builtin_bit_cast(f16x8, wmv[ks]);
#pragma unroll
          for (int jt = 0; jt < 8; ++jt)
            acc[jt] = MFMA(fragL(lds, L_K, jt * 2 + ks, lane), qm, acc[jt]);
        }
        if (l > 0) {
#pragma unroll
          for (int jt = 0; jt < 8; ++jt)
#pragma unroll
            for (int r = 0; r < 4; ++r)
              acc[jt][r] += h2f(af[q4][jt >> 1][((jt & 1) << 2) | r]);
        }
        float m = acc[0][0];
#pragma unroll
        for (int jt = 0; jt < 8; ++jt)
#pragma unroll
          for (int r = 0; r < 4; ++r) m = fmaxf(m, acc[jt][r]);
        m = fmaxf(m, __shfl_xor(m, 16)); m = fmaxf(m, __shfl_xor(m, 32));
        float s = 0.f;
#pragma unroll
        for (int jt = 0; jt < 8; ++jt)
#pragma unroll
          for (int r = 0; r < 4; ++r) { float e = __expf(acc[jt][r] - m); acc[jt][r] = e; s += e; }
        s += __shfl_xor(s, 16); s += __shfl_xor(s, 32);
        const float inv = 1.f / s;
#pragma unroll
        for (int jt = 0; jt < 8; ++jt)
#pragma unroll
          for (int r = 0; r < 4; ++r) acc[jt][r] *= inv;
#pragma unroll
        for (int ks3 = 0; ks3 < 4; ++ks3)
          af[q4][ks3] = pack8(acc[2 * ks3], acc[2 * ks3 + 1]);
      }
    }
    // no barrier: P3 reads L_V (ready) + own af; writes L_O (disjoint from L_Q/L_K)

    // ---- P3: o_g = v_g^T-frags (A) x p (B=af) -> L_O frags ----
    {
      const int g = wv >> 1, ih = wv & 1;
#pragma unroll
      for (int q4 = 0; q4 < 4; ++q4) {
        const int ti = ih * 4 + q4;
        f32x4 a = Z4;
#pragma unroll
        for (int ks = 0; ks < 4; ++ks)
          a = MFMA(fragL(lds, L_V, g * 4 + ks, lane), af[q4][ks], a);
        *(s16x4*)(lds + L_O + (((ti * 2 + (g >> 1)) << 10) | (lane << 4) | ((g & 1) << 3))) = pack4(a);
      }
    }
    __syncthreads();

    // ---- P4: r = o@Wo (Wo as A, o as B); h = LN1(h + r) -> hr, hp ----
    {
      const char* wo = wfrag + OFF_WOB + l * 8192;
      s16x8 ofr[2];
      ofr[0] = fragL(lds, L_O, wv * 2 + 0, lane);
      ofr[1] = fragL(lds, L_O, wv * 2 + 1, lane);
      f32x4 vv[4];
      float s = 0.f;
#pragma unroll
      for (int nt = 0; nt < 4; ++nt) {
        f32x4 a = Z4;
        a = MFMA(fragG(wo, nt * 2 + 0, lane), ofr[0], a);
        a = MFMA(fragG(wo, nt * 2 + 1, lane), ofr[1], a);
#pragma unroll
        for (int r = 0; r < 4; ++r) { vv[nt][r] = hr[nt][r] + a[r]; s += vv[nt][r]; }
      }
      s += __shfl_xor(s, 16); s += __shfl_xor(s, 32);
      const float mu = s * 0.015625f;
      float sq = 0.f;
#pragma unroll
      for (int nt = 0; nt < 4; ++nt)
#pragma unroll
        for (int r = 0; r < 4; ++r) { float d = vv[nt][r] - mu; sq += d * d; }
      sq += __shfl_xor(sq, 16); sq += __shfl_xor(sq, 32);
      const float rs = rsqrtf(sq * 0.015625f + 1e-5f);
#pragma unroll
      for (int nt = 0; nt < 4; ++nt) {
        const float4 g4 = *(const float4*)&ln1_g[l * 64 + nt * 16 + g16 * 4];
        const float4 b4 = *(const float4*)&ln1_b[l * 64 + nt * 16 + g16 * 4];
#pragma unroll
        for (int r = 0; r < 4; ++r)
          hr[nt][r] = (vv[nt][r] - mu) * rs * (&g4.x)[r] + (&b4.x)[r];
      }
      hp[0] = pack8(hr[0], hr[1]);
      hp[1] = pack8(hr[2], hr[3]);
    }

    // ---- P5+P6 fused: u=h@W1+b1 -> GLU -> f (regs) -> h = LN2(h + f@W2 + b2) ----
    {
      const char* w1 = wfrag + OFF_W1B + l * 32768;
      const char* w2 = wfrag + OFF_W2B + l * 16384;
      f32x4 acc6[4];
#pragma unroll
      for (int nt = 0; nt < 4; ++nt) acc6[nt] = Z4;
#pragma unroll
      for (int ks6 = 0; ks6 < 4; ++ks6) {
        union { unsigned u[4]; s16x8 s; } fb;
#pragma unroll
        for (int half = 0; half < 2; ++half) {
          const int mtp = ks6 * 2 + half;
          f32x4 a1 = Z4, a2 = Z4;
#pragma unroll
          for (int ks = 0; ks < 2; ++ks) {
            a1 = MFMA(fragG(w1, mtp * 2 + ks, lane), hp[ks], a1);
            a2 = MFMA(fragG(w1, (mtp + 8) * 2 + ks, lane), hp[ks], a2);
          }
          const float4 bb1 = *(const float4*)&b1[l * 256 + mtp * 16 + g16 * 4];
          const float4 bb2 = *(const float4*)&b1[l * 256 + 128 + mtp * 16 + g16 * 4];
          float fv[4];
#pragma unroll
          for (int r = 0; r < 4; ++r) {
            const float u1 = a1[r] + (&bb1.x)[r], u2 = a2[r] + (&bb2.x)[r];
            fv[r] = u1 * geluf(u2) + u2 * geluf(u1);
          }
          fb.u[half * 2 + 0] = pk_u32(fv[0], fv[1]);
          fb.u[half * 2 + 1] = pk_u32(fv[2], fv[3]);
        }
#pragma unroll
        for (int nt = 0; nt < 4; ++nt)
          acc6[nt] = MFMA(fragG(w2, nt * 4 + ks6, lane), fb.s, acc6[nt]);
      }
      // residual + b2 + LN2
      f32x4 vv[4];
      float s = 0.f;
#pragma unroll
      for (int nt = 0; nt < 4; ++nt) {
        const float4 bb = *(const float4*)&b2[l * 64 + nt * 16 + g16 * 4];
#pragma unroll
        for (int r = 0; r < 4; ++r) { vv[nt][r] = hr[nt][r] + acc6[nt][r] + (&bb.x)[r]; s += vv[nt][r]; }
      }
      s += __shfl_xor(s, 16); s += __shfl_xor(s, 32);
      const float mu = s * 0.015625f;
      float sq = 0.f;
#pragma unroll
      for (int nt = 0; nt < 4; ++nt)
#pragma unroll
        for (int r = 0; r < 4; ++r) { float d = vv[nt][r] - mu; sq += d * d; }
      sq += __shfl_xor(sq, 16); sq += __shfl_xor(sq, 32);
      const float rs = rsqrtf(sq * 0.015625f + 1e-5f);
#pragma unroll
      for (int nt = 0; nt < 4; ++nt) {
        const float4 g4 = *(const float4*)&ln2_g[l * 64 + nt * 16 + g16 * 4];
        const float4 b4 = *(const float4*)&ln2_b[l * 64 + nt * 16 + g16 * 4];
#pragma unroll
        for (int r = 0; r < 4; ++r)
          hr[nt][r] = (vv[nt][r] - mu) * rs * (&g4.x)[r] + (&b4.x)[r];
      }
      hp[0] = pack8(hr[0], hr[1]);
      hp[1] = pack8(hr[2], hr[3]);
    }
  }

  // ---- classifier head on row 127 ----
  float* scr = (float*)(lds + L_Q);
  if (wv == 7 && l15 == 15) {
#pragma unroll
    for (int nt = 0; nt < 4; ++nt)
#pragma unroll
      for (int r = 0; r < 4; ++r) scr[nt * 16 + g16 * 4 + r] = hr[nt][r];
  }
  __syncthreads();
  if (wv == 0) {
    const float hc = scr[lane];
    float lg[11];
#pragma unroll
    for (int kc = 0; kc < 11; ++kc) {
      float p = hc * Wc[lane * 11 + kc];
      p += __shfl_xor(p, 1);  p += __shfl_xor(p, 2);  p += __shfl_xor(p, 4);
      p += __shfl_xor(p, 8);  p += __shfl_xor(p, 16); p += __shfl_xor(p, 32);
      lg[kc] = p + bc[kc];
    }
    float mx = lg[0];
#pragma unroll
    for (int kc = 1; kc < 11; ++kc) mx = fmaxf(mx, lg[kc]);
    float s = 0.f;
#pragma unroll
    for (int kc = 0; kc < 11; ++kc) s += __expf(lg[kc] - mx);
    const float inv = 1.f / s;
    if (lane < 11) out[b * 11 + lane] = __expf(lg[lane] - mx) * inv;
  }
}

extern "C" void kernel_launch(void* const* d_in, const int* in_sizes, int n_in,
                              void* d_out, int out_size, void* d_ws, size_t ws_size,
                              hipStream_t stream) {
  const float* x         = (const float*)d_in[0];
  const float* frame_W   = (const float*)d_in[1];
  const float* cls_token = (const float*)d_in[2];
  const float* pos_embed = (const float*)d_in[3];
  const float* Wq        = (const float*)d_in[4];
  const float* Wk        = (const float*)d_in[5];
  const float* Wv        = (const float*)d_in[6];
  const float* Wmix      = (const float*)d_in[7];
  const float* Wo        = (const float*)d_in[8];
  const float* ln1_g     = (const float*)d_in[9];
  const float* ln1_b     = (const float*)d_in[10];
  const float* ln2_g     = (const float*)d_in[11];
  const float* ln2_b     = (const float*)d_in[12];
  const float* W1        = (const float*)d_in[13];
  const float* b1        = (const float*)d_in[14];
  const float* W2        = (const float*)d_in[15];
  const float* b2        = (const float*)d_in[16];
  const float* Wc        = (const float*)d_in[17];
  const float* bc        = (const float*)d_in[18];
  float* out = (float*)d_out;
  char* wfrag = (char*)d_ws;  // 663,552 B of f16 weight fragments

  prep_all<<<162, 256, 0, stream>>>(frame_W, Wq, Wk, Wv, Wo, W1, W2, wfrag);

  (void)hipFuncSetAttribute((const void*)feat_fwd, hipFuncAttributeMaxDynamicSharedMemorySize, LDS_BYTES);
  feat_fwd<<<dim3(256), dim3(512), LDS_BYTES, stream>>>(
      x, cls_token, pos_embed, Wmix, ln1_g, ln1_b, ln2_g, ln2_b,
      b1, b2, Wc, bc, out, wfrag);
}